// Round 1
// baseline (622.144 us; speedup 1.0000x reference)
//
#include <hip/hip_runtime.h>

typedef __attribute__((ext_vector_type(8))) short v8s;   // 8 x bf16 bits
typedef __attribute__((ext_vector_type(4))) float v4f;   // MFMA accumulator

#define MFMA16(a, b, c) __builtin_amdgcn_mfma_f32_16x16x32_bf16((a), (b), (c), 0, 0, 0)

__device__ __forceinline__ short f2bf(float f) {
    unsigned u = __float_as_uint(f);
    u += 0x7FFFu + ((u >> 16) & 1u);          // round-to-nearest-even
    return (short)(u >> 16);
}
__device__ __forceinline__ float bf2f(short s) {
    return __uint_as_float(((unsigned)(unsigned short)s) << 16);
}
__device__ __forceinline__ float bfly16(float v) {
#pragma unroll
    for (int m = 1; m < 16; m <<= 1) v += __shfl_xor(v, m);
    return v;
}

// ---------------------------------------------------------------------------
// Weight prep: bf16 B-fragments for all MFMA GEMMs + transposed f32 p1/p2.
// ws layout (shorts): [0) wsp 16384 | [16384) wge | [32768) wtm |
//   [49152) gatW 4096 | [53248) inW 12288 | [65536) outW 4096  (total 69632)
// then f32: p1T[64][32] (2048 f), p2T[32][16] (512 f)
// frag element: ws[((nb*KK+kk)*64 + l)*8 + j] = bf16(W[nb*16+(l&15)][kk*32+(l>>4)*8+j])
// ---------------------------------------------------------------------------
__global__ void giman_prep(const float* __restrict__ Wsp, const float* __restrict__ Wge,
                           const float* __restrict__ Wtm, const float* __restrict__ gatW,
                           const float* __restrict__ inw, const float* __restrict__ outw,
                           const float* __restrict__ p1w, const float* __restrict__ p2w,
                           short* __restrict__ ws) {
    int idx = blockIdx.x * 256 + threadIdx.x;
    if (idx < 69632) {
        const float* W; int off, KK, ldw;
        if (idx < 16384)      { W = Wsp;  off = idx;         KK = 8; ldw = 256; }
        else if (idx < 32768) { W = Wge;  off = idx - 16384; KK = 8; ldw = 256; }
        else if (idx < 49152) { W = Wtm;  off = idx - 32768; KK = 8; ldw = 256; }
        else if (idx < 53248) { W = gatW; off = idx - 49152; KK = 2; ldw = 64;  }
        else if (idx < 65536) { W = inw;  off = idx - 53248; KK = 2; ldw = 64;  }
        else                  { W = outw; off = idx - 65536; KK = 2; ldw = 64;  }
        int j = off & 7, l = (off >> 3) & 63, t = off >> 9;
        int kk = t % KK, nb = t / KK;
        int row = nb * 16 + (l & 15);
        int col = kk * 32 + ((l >> 4) << 3) + j;
        ws[idx] = f2bf(W[row * ldw + col]);
    } else if (idx < 71680) {
        int i = idx - 69632; int c = i >> 5, o = i & 31;
        float* p1T = (float*)(ws + 69632);
        p1T[i] = p1w[o * 64 + c];
    } else if (idx < 72192) {
        int i = idx - 71680; int c = i >> 4, o = i & 15;
        float* p2T = (float*)(ws + 69632) + 2048;
        p2T[i] = p2w[o * 32 + c];
    }
}

// ---------------------------------------------------------------------------
// Fused main kernel. 256 threads = 4 waves; each wave owns 16 samples
// end-to-end. All LDS is wave-private -> no __syncthreads anywhere.
// ---------------------------------------------------------------------------
__global__ __launch_bounds__(256)
void giman_main(const float* __restrict__ spatial, const float* __restrict__ genomic,
                const float* __restrict__ temporal, const float* __restrict__ adj,
                const short* __restrict__ wf,
                const float* __restrict__ p1T, const float* __restrict__ p2T,
                const float* __restrict__ bsp, const float* __restrict__ bge,
                const float* __restrict__ btm, const float* __restrict__ gat_a,
                const float* __restrict__ in_b, const float* __restrict__ out_b,
                const float* __restrict__ ln_g, const float* __restrict__ ln_b,
                const float* __restrict__ p1b, const float* __restrict__ p2b,
                const float* __restrict__ p3w, const float* __restrict__ p3bb,
                float* __restrict__ dout, int Btot)
{
    __shared__ __align__(16) short x_lds[4][48][72];  // [wave][16 samp * 3 nodes][64+8 pad]
    __shared__ __align__(16) short o_lds[4][16][72];  // [wave][4 samp * 4 pad rows][64+8]

    const int wv   = threadIdx.x >> 6;
    const int lane = threadIdx.x & 63;
    const int lq   = lane & 15;       // quarter-lane
    const int lg   = lane >> 4;       // lane group 0..3
    const int s0   = blockIdx.x * 64 + wv * 16;
    if (s0 + 16 > Btot) return;

    short (*xw)[72] = x_lds[wv];
    short (*ow)[72] = o_lds[wv];

    // ---- per-lane constants (col = nb*16+lq) ----
    float a1v[4], a2v[4], obv[4], lgv[4], lbv[4], ibv[12];
#pragma unroll
    for (int nb = 0; nb < 4; ++nb) {
        int c = nb * 16 + lq;
        a1v[nb] = gat_a[c & 31];
        a2v[nb] = gat_a[32 + (c & 31)];
        obv[nb] = out_b[c];
        lgv[nb] = ln_g[c];
        lbv[nb] = ln_b[c];
    }
#pragma unroll
    for (int nb = 0; nb < 12; ++nb) ibv[nb] = in_b[nb * 16 + lq];
    const float pb1a = p1b[lq], pb1b = p1b[lq + 16], pb2 = p2b[lq];
    const float p3w0 = p3w[lq], p3w1 = p3w[16 + lq];
    const float p3b0 = p3bb[0], p3b1 = p3bb[1];
    const float inv3 = 1.f / 3.f;

    // ================= Phase 1: modality projections (K=256) =================
    {
        const float* Xs[3] = {spatial, genomic, temporal};
        const float* Bs[3] = {bsp, bge, btm};
#pragma unroll
        for (int m = 0; m < 3; ++m) {
            const float* X = Xs[m] + (size_t)(s0 + lq) * 256 + lg * 8;
            const v8s* bwf = (const v8s*)(wf + m * 16384);
            v4f acc[4];
#pragma unroll
            for (int nb = 0; nb < 4; ++nb) acc[nb] = (v4f){0.f, 0.f, 0.f, 0.f};
#pragma unroll
            for (int kk = 0; kk < 8; ++kk) {
                float4 u = *(const float4*)(X + kk * 32);
                float4 v = *(const float4*)(X + kk * 32 + 4);
                v8s af;
                af[0] = f2bf(u.x); af[1] = f2bf(u.y); af[2] = f2bf(u.z); af[3] = f2bf(u.w);
                af[4] = f2bf(v.x); af[5] = f2bf(v.y); af[6] = f2bf(v.z); af[7] = f2bf(v.w);
#pragma unroll
                for (int nb = 0; nb < 4; ++nb)
                    acc[nb] = MFMA16(af, bwf[(nb * 8 + kk) * 64 + lane], acc[nb]);
            }
#pragma unroll
            for (int nb = 0; nb < 4; ++nb) {
                float bb = Bs[m][nb * 16 + lq];
#pragma unroll
                for (int r = 0; r < 4; ++r) {
                    float v = acc[nb][r] + bb;
                    v = v > 0.f ? v : 0.f;                       // ReLU
                    xw[(lg * 4 + r) * 3 + m][nb * 16 + lq] = f2bf(v);
                }
            }
        }
    }

    // ================= Phase 2: per 4-sample tile =================
    const v8s* gwf = (const v8s*)(wf + 49152);
    const v8s* iwf = (const v8s*)(wf + 53248);
    const v8s* owf = (const v8s*)(wf + 65536);

    for (int t = 0; t < 4; ++t) {
        const int s = s0 + t * 4 + lg;   // this quarter's sample

        // A-fragments of x for padded tile (rows: 4 per sample, node clamped)
        int rn = lq & 3; rn = (rn == 3) ? 2 : rn;
        const short* xrp = xw[(t * 4 + (lq >> 2)) * 3 + rn];
        v8s xa0 = *(const v8s*)(xrp + lg * 8);
        v8s xa1 = *(const v8s*)(xrp + 32 + lg * 8);

        // ---- GAT: h = x @ gatW^T ----
        v4f hacc[4];
#pragma unroll
        for (int nb = 0; nb < 4; ++nb) {
            v4f a = (v4f){0.f, 0.f, 0.f, 0.f};
            a = MFMA16(xa0, gwf[(nb * 2 + 0) * 64 + lane], a);
            a = MFMA16(xa1, gwf[(nb * 2 + 1) * 64 + lane], a);
            hacc[nb] = a;
        }

        // ---- GAT attention (lane holds sample lg: 3 node rows x 4 cols) ----
        float ei[3][2] = {}, ej[3][2] = {};
#pragma unroll
        for (int nb = 0; nb < 4; ++nb) {
            int h = nb >> 1;
#pragma unroll
            for (int n = 0; n < 3; ++n) {
                ei[n][h] += hacc[nb][n] * a1v[nb];
                ej[n][h] += hacc[nb][n] * a2v[nb];
            }
        }
#pragma unroll
        for (int n = 0; n < 3; ++n)
#pragma unroll
            for (int h = 0; h < 2; ++h) { ei[n][h] = bfly16(ei[n][h]); ej[n][h] = bfly16(ej[n][h]); }

        float am[3][3];
#pragma unroll
        for (int i = 0; i < 3; ++i)
#pragma unroll
            for (int j = 0; j < 3; ++j) am[i][j] = adj[(size_t)s * 9 + i * 3 + j];

        float wj0[2] = {}, wj1[2] = {}, wj2[2] = {};
#pragma unroll
        for (int h = 0; h < 2; ++h)
#pragma unroll
            for (int i = 0; i < 3; ++i) {
                float e0 = ei[i][h] + ej[0][h]; e0 = e0 > 0.f ? e0 : 0.2f * e0; if (am[i][0] == 0.f) e0 = -1e9f;
                float e1 = ei[i][h] + ej[1][h]; e1 = e1 > 0.f ? e1 : 0.2f * e1; if (am[i][1] == 0.f) e1 = -1e9f;
                float e2 = ei[i][h] + ej[2][h]; e2 = e2 > 0.f ? e2 : 0.2f * e2; if (am[i][2] == 0.f) e2 = -1e9f;
                float mx = fmaxf(e0, fmaxf(e1, e2));
                float q0 = __expf(e0 - mx), q1 = __expf(e1 - mx), q2 = __expf(e2 - mx);
                float inv = 1.f / (q0 + q1 + q2);
                wj0[h] += q0 * inv; wj1[h] += q1 * inv; wj2[h] += q2 * inv;
            }
        float gp[4];
#pragma unroll
        for (int nb = 0; nb < 4; ++nb) {
            int h = nb >> 1;
            gp[nb] = (wj0[h] * hacc[nb][0] + wj1[h] * hacc[nb][1] + wj2[h] * hacc[nb][2]) * inv3;
        }

        // ---- qkv = x @ inW^T + in_b ----
        v4f qkv[12];
#pragma unroll
        for (int nb = 0; nb < 12; ++nb) {
            float bb = ibv[nb];
            v4f a = (v4f){bb, bb, bb, bb};
            a = MFMA16(xa0, iwf[(nb * 2 + 0) * 64 + lane], a);
            a = MFMA16(xa1, iwf[(nb * 2 + 1) * 64 + lane], a);
            qkv[nb] = a;
        }

        // ---- MHA: scores, softmax, o ----
        float sc[2][3][3];
#pragma unroll
        for (int h = 0; h < 2; ++h)
#pragma unroll
            for (int i = 0; i < 3; ++i)
#pragma unroll
                for (int j = 0; j < 3; ++j)
                    sc[h][i][j] = qkv[2 * h][i] * qkv[4 + 2 * h][j] + qkv[2 * h + 1][i] * qkv[5 + 2 * h][j];
#pragma unroll
        for (int h = 0; h < 2; ++h)
#pragma unroll
            for (int i = 0; i < 3; ++i)
#pragma unroll
                for (int j = 0; j < 3; ++j) sc[h][i][j] = bfly16(sc[h][i][j]);

        float al[2][3][3];
#pragma unroll
        for (int h = 0; h < 2; ++h)
#pragma unroll
            for (int i = 0; i < 3; ++i) {
                float e0 = sc[h][i][0] * 0.17677669529663687f;
                float e1 = sc[h][i][1] * 0.17677669529663687f;
                float e2 = sc[h][i][2] * 0.17677669529663687f;
                float mx = fmaxf(e0, fmaxf(e1, e2));
                float q0 = __expf(e0 - mx), q1 = __expf(e1 - mx), q2 = __expf(e2 - mx);
                float inv = 1.f / (q0 + q1 + q2);
                al[h][i][0] = q0 * inv; al[h][i][1] = q1 * inv; al[h][i][2] = q2 * inv;
            }
#pragma unroll
        for (int nb = 0; nb < 4; ++nb) {
            int h = nb >> 1;
#pragma unroll
            for (int i = 0; i < 3; ++i) {
                float o = al[h][i][0] * qkv[8 + nb][0] + al[h][i][1] * qkv[8 + nb][1]
                        + al[h][i][2] * qkv[8 + nb][2];
                ow[lg * 4 + i][nb * 16 + lq] = f2bf(o);
            }
        }

        // ---- attn_out = o @ outW^T + out_b, residual folded into acc init ----
        int on = lq & 3; on = (on == 3) ? 2 : on;
        const short* orp = ow[(lq & 12) + on];
        v8s oa0 = *(const v8s*)(orp + lg * 8);
        v8s oa1 = *(const v8s*)(orp + 32 + lg * 8);
        v4f y[4];
#pragma unroll
        for (int nb = 0; nb < 4; ++nb) {
            v4f a;
            a[0] = bf2f(xw[(t * 4 + lg) * 3 + 0][nb * 16 + lq]) + obv[nb];
            a[1] = bf2f(xw[(t * 4 + lg) * 3 + 1][nb * 16 + lq]) + obv[nb];
            a[2] = bf2f(xw[(t * 4 + lg) * 3 + 2][nb * 16 + lq]) + obv[nb];
            a[3] = 0.f;
            a = MFMA16(oa0, owf[(nb * 2 + 0) * 64 + lane], a);
            a = MFMA16(oa1, owf[(nb * 2 + 1) * 64 + lane], a);
            y[nb] = a;
        }

        // ---- LayerNorm per node row + cross-modal mean + combined ----
        float comb[4];
        {
            float mu[3], rs[3];
#pragma unroll
            for (int r = 0; r < 3; ++r) {
                float sm = y[0][r] + y[1][r] + y[2][r] + y[3][r];
                float sq = y[0][r] * y[0][r] + y[1][r] * y[1][r]
                         + y[2][r] * y[2][r] + y[3][r] * y[3][r];
                sm = bfly16(sm); sq = bfly16(sq);
                float m_ = sm * (1.f / 64.f);
                float var = sq * (1.f / 64.f) - m_ * m_;
                mu[r] = m_;
                rs[r] = rsqrtf(var + 1e-5f);
            }
#pragma unroll
            for (int nb = 0; nb < 4; ++nb) {
                float cm = (y[nb][0] - mu[0]) * rs[0] + (y[nb][1] - mu[1]) * rs[1]
                         + (y[nb][2] - mu[2]) * rs[2];
                comb[nb] = gp[nb] + cm * inv3 * lgv[nb] + lbv[nb];
            }
        }

        // ---- predictor 64->32->16->2 (o region reused as scratch) ----
        {
            float* cbuf = (float*)&ow[0][0];   // [4][68]
            float* zbuf = cbuf + 272;          // [4][34]
#pragma unroll
            for (int nb = 0; nb < 4; ++nb) cbuf[lg * 68 + nb * 16 + lq] = comb[nb];
#pragma unroll
            for (int rep = 0; rep < 2; ++rep) {
                int o1 = lq + rep * 16;
                float a = (rep == 0) ? pb1a : pb1b;
#pragma unroll 8
                for (int c = 0; c < 64; ++c)
                    a = fmaf(cbuf[lg * 68 + c], p1T[c * 32 + o1], a);
                zbuf[lg * 34 + o1] = a > 0.f ? a : 0.f;
            }
            float z2;
            {
                float a = pb2;
#pragma unroll
                for (int c = 0; c < 32; ++c)
                    a = fmaf(zbuf[lg * 34 + c], p2T[c * 16 + lq], a);
                z2 = a > 0.f ? a : 0.f;
            }
            float po0 = p3w0 * z2;
            float po1 = p3w1 * z2;
            po0 = bfly16(po0); po1 = bfly16(po1);
            if (lq == 0) {
                dout[s] = po0 + p3b0;
                dout[Btot + s] = po1 + p3b1;
            }
        }
    }
}

extern "C" void kernel_launch(void* const* d_in, const int* in_sizes, int n_in,
                              void* d_out, int out_size, void* d_ws, size_t ws_size,
                              hipStream_t stream) {
    const float* spatial  = (const float*)d_in[0];
    const float* genomic  = (const float*)d_in[1];
    const float* temporal = (const float*)d_in[2];
    const float* adj      = (const float*)d_in[3];
    const float* Wsp = (const float*)d_in[4];
    const float* bsp = (const float*)d_in[5];
    const float* Wge = (const float*)d_in[6];
    const float* bge = (const float*)d_in[7];
    const float* Wtm = (const float*)d_in[8];
    const float* btm = (const float*)d_in[9];
    const float* gatW  = (const float*)d_in[10];
    const float* gat_a = (const float*)d_in[11];
    const float* in_w  = (const float*)d_in[12];
    const float* in_b  = (const float*)d_in[13];
    const float* out_w = (const float*)d_in[14];
    const float* out_b = (const float*)d_in[15];
    const float* ln_g  = (const float*)d_in[16];
    const float* ln_b  = (const float*)d_in[17];
    const float* p1w = (const float*)d_in[18];
    const float* p1b = (const float*)d_in[19];
    const float* p2w = (const float*)d_in[20];
    const float* p2b = (const float*)d_in[21];
    const float* p3w = (const float*)d_in[22];
    const float* p3b = (const float*)d_in[23];
    float* out = (float*)d_out;
    const int Btot = in_sizes[0] / 256;

    short* wf  = (short*)d_ws;
    float* p1T = (float*)((char*)d_ws + 69632 * 2);
    float* p2T = p1T + 2048;

    giman_prep<<<(72192 + 255) / 256, 256, 0, stream>>>(Wsp, Wge, Wtm, gatW, in_w, out_w,
                                                        p1w, p2w, wf);
    giman_main<<<Btot / 64, 256, 0, stream>>>(spatial, genomic, temporal, adj,
                                              wf, p1T, p2T, bsp, bge, btm, gat_a,
                                              in_b, out_b, ln_g, ln_b,
                                              p1b, p2b, p3w, p3b, out, Btot);
}

// Round 2
// 431.944 us; speedup vs baseline: 1.4403x; 1.4403x over previous
//
#include <hip/hip_runtime.h>

typedef __attribute__((ext_vector_type(8))) short v8s;   // 8 x bf16 bits
typedef __attribute__((ext_vector_type(4))) float v4f;   // MFMA accumulator

#define MFMA16(a, b, c) __builtin_amdgcn_mfma_f32_16x16x32_bf16((a), (b), (c), 0, 0, 0)

__device__ __forceinline__ short f2bf(float f) {
    unsigned u = __float_as_uint(f);
    u += 0x7FFFu + ((u >> 16) & 1u);          // round-to-nearest-even
    return (short)(u >> 16);
}
__device__ __forceinline__ float bf2f(short s) {
    return __uint_as_float(((unsigned)(unsigned short)s) << 16);
}
__device__ __forceinline__ float bfly16(float v) {
#pragma unroll
    for (int m = 1; m < 16; m <<= 1) v += __shfl_xor(v, m);
    return v;
}

// ---------------------------------------------------------------------------
// Weight prep. ws layout (shorts):
//   [0)      wsp frags 16384      (nb0..3, kk0..7)
//   [16384)  wge frags 16384
//   [32768)  wtm frags 16384
//   [49152)  gatW frags 4096      (nb0..3, kk0..1)
//   [53248)  q,k frags 8192       (in_w rows 0..127: nb0..7, kk0..1)
//   [61440)  u frags 8192         (M_h = outW_h @ Wv_h: h0..1, nb0..3, kk0..1)
//   [69632)  p1 frags 2048        (nb0..1, kk0..1)
//   [71680)  p2 frags 512         (nb0, kk0)
//   [72192)  cb[64] f32           (out_b + out_w[:,v-part] @ in_b[v-part])
// frag element: ws[base + ((t)*64 + l)*8 + j] = bf16(W[nb*16+(l&15)][kk*32+(l>>4)*8+j])
// ---------------------------------------------------------------------------
__global__ void giman_prep(const float* __restrict__ Wsp, const float* __restrict__ Wge,
                           const float* __restrict__ Wtm, const float* __restrict__ gatW,
                           const float* __restrict__ inw, const float* __restrict__ outw,
                           const float* __restrict__ p1w, const float* __restrict__ p2w,
                           const float* __restrict__ in_b, const float* __restrict__ out_b,
                           short* __restrict__ ws) {
    int idx = blockIdx.x * 256 + threadIdx.x;
    if (idx < 72192) {
        int j = idx & 7, l = (idx >> 3) & 63;
        int lr = l & 15, lc = ((l >> 4) << 3) + j;
        float val;
        if (idx < 49152) {
            const float* W; int off;
            if (idx < 16384)      { W = Wsp; off = idx; }
            else if (idx < 32768) { W = Wge; off = idx - 16384; }
            else                  { W = Wtm; off = idx - 32768; }
            int t = off >> 9, kk = t & 7, nb = t >> 3;
            val = W[(nb * 16 + lr) * 256 + kk * 32 + lc];
        } else if (idx < 53248) {
            int t = (idx - 49152) >> 9, kk = t & 1, nb = t >> 1;
            val = gatW[(nb * 16 + lr) * 64 + kk * 32 + lc];
        } else if (idx < 61440) {
            int t = (idx - 53248) >> 9, kk = t & 1, nb = t >> 1;
            val = inw[(nb * 16 + lr) * 64 + kk * 32 + lc];
        } else if (idx < 69632) {
            int t = (idx - 61440) >> 9, kk = t & 1, nbh = t >> 1;
            int h = nbh >> 2, nb = nbh & 3;
            int r = nb * 16 + lr, c = kk * 32 + lc;
            float s = 0.f;
            for (int k = 0; k < 32; ++k)
                s += outw[r * 64 + h * 32 + k] * inw[(128 + h * 32 + k) * 64 + c];
            val = s;
        } else if (idx < 71680) {
            int t = (idx - 69632) >> 9, kk = t & 1, nb = t >> 1;
            val = p1w[(nb * 16 + lr) * 64 + kk * 32 + lc];
        } else {
            val = p2w[lr * 32 + lc];
        }
        ws[idx] = f2bf(val);
    } else if (idx < 72256) {
        int r = idx - 72192;
        float s = out_b[r];
        for (int k = 0; k < 64; ++k) s += outw[r * 64 + 128 + k] * in_b[128 + k];
        ((float*)(ws + 72192))[r] = s;
    }
}

// ---------------------------------------------------------------------------
// Fused main kernel. 256 threads = 4 waves; each wave owns 16 samples
// end-to-end. All LDS wave-private -> no __syncthreads.
// ---------------------------------------------------------------------------
__global__ __launch_bounds__(256, 3)
void giman_main(const float* __restrict__ spatial, const float* __restrict__ genomic,
                const float* __restrict__ temporal, const float* __restrict__ adj,
                const short* __restrict__ wf,
                const float* __restrict__ bsp, const float* __restrict__ bge,
                const float* __restrict__ btm, const float* __restrict__ gat_a,
                const float* __restrict__ in_b, const float* __restrict__ ln_g,
                const float* __restrict__ ln_b, const float* __restrict__ p1b,
                const float* __restrict__ p2b, const float* __restrict__ p3w,
                const float* __restrict__ p3bb,
                float* __restrict__ dout, int Btot)
{
    __shared__ __align__(16) short x_lds[4][48][72];  // x (16 samp x 3 nodes)
    __shared__ __align__(16) short c_lds[4][16][72];  // combined (16 samp x 64)
    __shared__ __align__(16) short z_lds[4][16][40];  // z1 (16 samp x 32)
    __shared__ __align__(16) float a_lds[4][148];     // adj (16 samp x 9)

    const int wv   = threadIdx.x >> 6;
    const int lane = threadIdx.x & 63;
    const int lq   = lane & 15;
    const int lg   = lane >> 4;
    const int s0   = blockIdx.x * 64 + wv * 16;
    if (s0 + 16 > Btot) return;

    short (*xw)[72] = x_lds[wv];

    // prefetch adj for all 16 samples (hidden under phase 1)
    if (lane < 36)
        *(float4*)&a_lds[wv][lane * 4] = *(const float4*)(adj + (size_t)s0 * 9 + lane * 4);

    // ---- per-lane constants (col = nb*16+lq) ----
    const float* cbp = (const float*)(wf + 72192);
    float a1v[4], a2v[4], cbv[4], lgv[4], lbv[4], ibv[8];
#pragma unroll
    for (int nb = 0; nb < 4; ++nb) {
        int c = nb * 16 + lq;
        a1v[nb] = gat_a[c & 31];
        a2v[nb] = gat_a[32 + (c & 31)];
        cbv[nb] = cbp[c];
        lgv[nb] = ln_g[c];
        lbv[nb] = ln_b[c];
    }
#pragma unroll
    for (int nb = 0; nb < 8; ++nb) ibv[nb] = in_b[nb * 16 + lq];
    const float pb1v0 = p1b[lq], pb1v1 = p1b[16 + lq], pb2v = p2b[lq];
    const float p3w0 = p3w[lq], p3w1 = p3w[16 + lq];
    const float p3b0 = p3bb[0], p3b1 = p3bb[1];
    const float inv3 = 1.f / 3.f;

    // ================= Phase 1: modality projections (K=256) =================
    {
        const float* Xs[3] = {spatial, genomic, temporal};
        const float* Bs[3] = {bsp, bge, btm};
#pragma unroll
        for (int m = 0; m < 3; ++m) {
            const float* X = Xs[m] + (size_t)(s0 + lq) * 256 + lg * 8;
            const v8s* bwf = (const v8s*)(wf + m * 16384);
            v4f acc[4];
#pragma unroll
            for (int nb = 0; nb < 4; ++nb) acc[nb] = (v4f){0.f, 0.f, 0.f, 0.f};
#pragma unroll 4
            for (int kk = 0; kk < 8; ++kk) {
                float4 u = *(const float4*)(X + kk * 32);
                float4 v = *(const float4*)(X + kk * 32 + 4);
                v8s af;
                af[0] = f2bf(u.x); af[1] = f2bf(u.y); af[2] = f2bf(u.z); af[3] = f2bf(u.w);
                af[4] = f2bf(v.x); af[5] = f2bf(v.y); af[6] = f2bf(v.z); af[7] = f2bf(v.w);
#pragma unroll
                for (int nb = 0; nb < 4; ++nb)
                    acc[nb] = MFMA16(af, bwf[(nb * 8 + kk) * 64 + lane], acc[nb]);
            }
#pragma unroll
            for (int nb = 0; nb < 4; ++nb) {
                float bb = Bs[m][nb * 16 + lq];
#pragma unroll
                for (int r = 0; r < 4; ++r) {
                    float v = acc[nb][r] + bb;
                    v = v > 0.f ? v : 0.f;                       // ReLU
                    xw[(lg * 4 + r) * 3 + m][nb * 16 + lq] = f2bf(v);
                }
            }
        }
    }

    // ================= Phase 2: per 4-sample tile =================
    const v8s* gwf = (const v8s*)(wf + 49152);
    const v8s* qkf = (const v8s*)(wf + 53248);
    const v8s* uf  = (const v8s*)(wf + 61440);

#pragma unroll 1
    for (int t = 0; t < 4; ++t) {
        // A-fragments of x (rows: 4 per sample, node clamped)
        int rn = lq & 3; rn = (rn == 3) ? 2 : rn;
        const short* xrp = xw[(t * 4 + (lq >> 2)) * 3 + rn];
        v8s xa0 = *(const v8s*)(xrp + lg * 8);
        v8s xa1 = *(const v8s*)(xrp + 32 + lg * 8);

        // ---- GAT: h = x @ gatW^T ----
        v4f hacc[4];
#pragma unroll
        for (int nb = 0; nb < 4; ++nb) {
            v4f a = (v4f){0.f, 0.f, 0.f, 0.f};
            a = MFMA16(xa0, gwf[(nb * 2 + 0) * 64 + lane], a);
            a = MFMA16(xa1, gwf[(nb * 2 + 1) * 64 + lane], a);
            hacc[nb] = a;
        }

        // ---- GAT attention (lane's C-rows = nodes of sample t*4+lg) ----
        float ei[3][2] = {}, ej[3][2] = {};
#pragma unroll
        for (int nb = 0; nb < 4; ++nb) {
            int h = nb >> 1;
#pragma unroll
            for (int n = 0; n < 3; ++n) {
                ei[n][h] += hacc[nb][n] * a1v[nb];
                ej[n][h] += hacc[nb][n] * a2v[nb];
            }
        }
#pragma unroll
        for (int n = 0; n < 3; ++n)
#pragma unroll
            for (int h = 0; h < 2; ++h) { ei[n][h] = bfly16(ei[n][h]); ej[n][h] = bfly16(ej[n][h]); }

        const float* amp = &a_lds[wv][(t * 4 + lg) * 9];
        float am[9];
#pragma unroll
        for (int q = 0; q < 9; ++q) am[q] = amp[q];

        float wj0[2] = {}, wj1[2] = {}, wj2[2] = {};
#pragma unroll
        for (int h = 0; h < 2; ++h)
#pragma unroll
            for (int i = 0; i < 3; ++i) {
                float e0 = ei[i][h] + ej[0][h]; e0 = e0 > 0.f ? e0 : 0.2f * e0; if (am[i * 3 + 0] == 0.f) e0 = -1e9f;
                float e1 = ei[i][h] + ej[1][h]; e1 = e1 > 0.f ? e1 : 0.2f * e1; if (am[i * 3 + 1] == 0.f) e1 = -1e9f;
                float e2 = ei[i][h] + ej[2][h]; e2 = e2 > 0.f ? e2 : 0.2f * e2; if (am[i * 3 + 2] == 0.f) e2 = -1e9f;
                float mx = fmaxf(e0, fmaxf(e1, e2));
                float q0 = __expf(e0 - mx), q1 = __expf(e1 - mx), q2 = __expf(e2 - mx);
                float inv = 1.f / (q0 + q1 + q2);
                wj0[h] += q0 * inv; wj1[h] += q1 * inv; wj2[h] += q2 * inv;
            }
        float gp[4];
#pragma unroll
        for (int nb = 0; nb < 4; ++nb) {
            int h = nb >> 1;
            gp[nb] = (wj0[h] * hacc[nb][0] + wj1[h] * hacc[nb][1] + wj2[h] * hacc[nb][2]) * inv3;
        }

        // ---- q,k = x @ inW[0:128]^T + b ----
        v4f qk[8];
#pragma unroll
        for (int nb = 0; nb < 8; ++nb) {
            float bb = ibv[nb];
            v4f a = (v4f){bb, bb, bb, bb};
            a = MFMA16(xa0, qkf[(nb * 2 + 0) * 64 + lane], a);
            a = MFMA16(xa1, qkf[(nb * 2 + 1) * 64 + lane], a);
            qk[nb] = a;
        }

        // ---- MHA scores + softmax ----
        float sc[2][3][3];
#pragma unroll
        for (int h = 0; h < 2; ++h)
#pragma unroll
            for (int i = 0; i < 3; ++i)
#pragma unroll
                for (int j = 0; j < 3; ++j)
                    sc[h][i][j] = qk[2 * h][i] * qk[4 + 2 * h][j] + qk[2 * h + 1][i] * qk[5 + 2 * h][j];
#pragma unroll
        for (int h = 0; h < 2; ++h)
#pragma unroll
            for (int i = 0; i < 3; ++i)
#pragma unroll
                for (int j = 0; j < 3; ++j) sc[h][i][j] = bfly16(sc[h][i][j]);

        float al[2][3][3];
#pragma unroll
        for (int h = 0; h < 2; ++h)
#pragma unroll
            for (int i = 0; i < 3; ++i) {
                float e0 = sc[h][i][0] * 0.17677669529663687f;
                float e1 = sc[h][i][1] * 0.17677669529663687f;
                float e2 = sc[h][i][2] * 0.17677669529663687f;
                float mx = fmaxf(e0, fmaxf(e1, e2));
                float q0 = __expf(e0 - mx), q1 = __expf(e1 - mx), q2 = __expf(e2 - mx);
                float inv = 1.f / (q0 + q1 + q2);
                al[h][i][0] = q0 * inv; al[h][i][1] = q1 * inv; al[h][i][2] = q2 * inv;
            }

        // ---- u_h = x @ M_h^T (outW folded into V) ----
        v4f u[2][4];
#pragma unroll
        for (int h = 0; h < 2; ++h)
#pragma unroll
            for (int nb = 0; nb < 4; ++nb) {
                v4f a = (v4f){0.f, 0.f, 0.f, 0.f};
                a = MFMA16(xa0, uf[((h * 4 + nb) * 2 + 0) * 64 + lane], a);
                a = MFMA16(xa1, uf[((h * 4 + nb) * 2 + 1) * 64 + lane], a);
                u[h][nb] = a;
            }

        // ---- y = x + attn_out + cb,  LayerNorm, combine with GAT ----
        float y[4][3];
#pragma unroll
        for (int nb = 0; nb < 4; ++nb)
#pragma unroll
            for (int r = 0; r < 3; ++r) {
                float v = bf2f(xw[(t * 4 + lg) * 3 + r][nb * 16 + lq]) + cbv[nb];
                v += al[0][r][0] * u[0][nb][0] + al[0][r][1] * u[0][nb][1] + al[0][r][2] * u[0][nb][2];
                v += al[1][r][0] * u[1][nb][0] + al[1][r][1] * u[1][nb][1] + al[1][r][2] * u[1][nb][2];
                y[nb][r] = v;
            }

        float mu[3], rs[3];
#pragma unroll
        for (int r = 0; r < 3; ++r) {
            float sm = y[0][r] + y[1][r] + y[2][r] + y[3][r];
            float sq = y[0][r] * y[0][r] + y[1][r] * y[1][r]
                     + y[2][r] * y[2][r] + y[3][r] * y[3][r];
            sm = bfly16(sm); sq = bfly16(sq);
            float m_ = sm * (1.f / 64.f);
            float var = sq * (1.f / 64.f) - m_ * m_;
            mu[r] = m_;
            rs[r] = rsqrtf(var + 1e-5f);
        }
#pragma unroll
        for (int nb = 0; nb < 4; ++nb) {
            float cm = (y[nb][0] - mu[0]) * rs[0] + (y[nb][1] - mu[1]) * rs[1]
                     + (y[nb][2] - mu[2]) * rs[2];
            float comb = gp[nb] + cm * inv3 * lgv[nb] + lbv[nb];
            c_lds[wv][t * 4 + lg][nb * 16 + lq] = f2bf(comb);
        }
    }

    // ================= Predictor 64->32->16->2 via MFMA =================
    {
        const v8s* p1f = (const v8s*)(wf + 69632);
        const v8s* p2f = (const v8s*)(wf + 71680);
        const short* crp = &c_lds[wv][lq][0];
        v8s ca0 = *(const v8s*)(crp + lg * 8);
        v8s ca1 = *(const v8s*)(crp + 32 + lg * 8);
        v4f z1[2];
#pragma unroll
        for (int nb = 0; nb < 2; ++nb) {
            float bb = nb ? pb1v1 : pb1v0;
            v4f a = (v4f){bb, bb, bb, bb};
            a = MFMA16(ca0, p1f[(nb * 2 + 0) * 64 + lane], a);
            a = MFMA16(ca1, p1f[(nb * 2 + 1) * 64 + lane], a);
            z1[nb] = a;
        }
#pragma unroll
        for (int nb = 0; nb < 2; ++nb)
#pragma unroll
            for (int r = 0; r < 4; ++r) {
                float v = z1[nb][r];
                v = v > 0.f ? v : 0.f;
                z_lds[wv][lg * 4 + r][nb * 16 + lq] = f2bf(v);
            }
        v8s za = *(const v8s*)(&z_lds[wv][lq][0] + lg * 8);
        v4f z2 = (v4f){pb2v, pb2v, pb2v, pb2v};
        z2 = MFMA16(za, p2f[lane], z2);
#pragma unroll
        for (int r = 0; r < 4; ++r) {
            float v = z2[r];
            v = v > 0.f ? v : 0.f;
            float po0 = bfly16(v * p3w0);
            float po1 = bfly16(v * p3w1);
            if (lq == 0) {
                dout[s0 + lg * 4 + r] = po0 + p3b0;
                dout[Btot + s0 + lg * 4 + r] = po1 + p3b1;
            }
        }
    }
}

extern "C" void kernel_launch(void* const* d_in, const int* in_sizes, int n_in,
                              void* d_out, int out_size, void* d_ws, size_t ws_size,
                              hipStream_t stream) {
    const float* spatial  = (const float*)d_in[0];
    const float* genomic  = (const float*)d_in[1];
    const float* temporal = (const float*)d_in[2];
    const float* adj      = (const float*)d_in[3];
    const float* Wsp = (const float*)d_in[4];
    const float* bsp = (const float*)d_in[5];
    const float* Wge = (const float*)d_in[6];
    const float* bge = (const float*)d_in[7];
    const float* Wtm = (const float*)d_in[8];
    const float* btm = (const float*)d_in[9];
    const float* gatW  = (const float*)d_in[10];
    const float* gat_a = (const float*)d_in[11];
    const float* in_w  = (const float*)d_in[12];
    const float* in_b  = (const float*)d_in[13];
    const float* out_w = (const float*)d_in[14];
    const float* out_b = (const float*)d_in[15];
    const float* ln_g  = (const float*)d_in[16];
    const float* ln_b  = (const float*)d_in[17];
    const float* p1w = (const float*)d_in[18];
    const float* p1b = (const float*)d_in[19];
    const float* p2w = (const float*)d_in[20];
    const float* p2b = (const float*)d_in[21];
    const float* p3w = (const float*)d_in[22];
    const float* p3b = (const float*)d_in[23];
    float* out = (float*)d_out;
    const int Btot = in_sizes[0] / 256;

    short* wf = (short*)d_ws;

    giman_prep<<<(72256 + 255) / 256, 256, 0, stream>>>(Wsp, Wge, Wtm, gatW, in_w, out_w,
                                                        p1w, p2w, in_b, out_b, wf);
    giman_main<<<Btot / 64, 256, 0, stream>>>(spatial, genomic, temporal, adj, wf,
                                              bsp, bge, btm, gat_a, in_b,
                                              ln_g, ln_b, p1b, p2b, p3w, p3b,
                                              out, Btot);
}

// Round 3
// 235.228 us; speedup vs baseline: 2.6449x; 1.8363x over previous
//
#include <hip/hip_runtime.h>

typedef __attribute__((ext_vector_type(8))) short v8s;   // 8 x bf16 bits
typedef __attribute__((ext_vector_type(4))) float v4f;   // MFMA accumulator

#define MFMA16(a, b, c) __builtin_amdgcn_mfma_f32_16x16x32_bf16((a), (b), (c), 0, 0, 0)

__device__ __forceinline__ short f2bf(float f) {
    unsigned u = __float_as_uint(f);
    u += 0x7FFFu + ((u >> 16) & 1u);          // round-to-nearest-even
    return (short)(u >> 16);
}
__device__ __forceinline__ float bf2f(short s) {
    return __uint_as_float(((unsigned)(unsigned short)s) << 16);
}
__device__ __forceinline__ float bfly16(float v) {
#pragma unroll
    for (int m = 1; m < 16; m <<= 1) v += __shfl_xor(v, m);
    return v;
}

// ---------------------------------------------------------------------------
// Weight prep. ws layout (shorts):
//   [0)      wsp frags 16384      (nb0..3, kk0..7)
//   [16384)  wge frags 16384
//   [32768)  wtm frags 16384
//   [49152)  gatW frags 4096      (nb0..3, kk0..1)
//   [53248)  q,k frags 8192       (in_w rows 0..127: nb0..7, kk0..1)
//   [61440)  u frags 8192         (M_h = outW_h @ Wv_h: h0..1, nb0..3, kk0..1)
//   [69632)  p1 frags 2048        (nb0..1, kk0..1)
//   [71680)  p2 frags 512         (nb0, kk0)
//   [72192)  cb[64] f32           (out_b + out_w[:,v-part] @ in_b[v-part])
// frag element: ws[base + ((t)*64 + l)*8 + j] = bf16(W[nb*16+(l&15)][kk*32+(l>>4)*8+j])
// ---------------------------------------------------------------------------
__global__ void giman_prep(const float* __restrict__ Wsp, const float* __restrict__ Wge,
                           const float* __restrict__ Wtm, const float* __restrict__ gatW,
                           const float* __restrict__ inw, const float* __restrict__ outw,
                           const float* __restrict__ p1w, const float* __restrict__ p2w,
                           const float* __restrict__ in_b, const float* __restrict__ out_b,
                           short* __restrict__ ws) {
    int idx = blockIdx.x * 256 + threadIdx.x;
    if (idx < 72192) {
        int j = idx & 7, l = (idx >> 3) & 63;
        int lr = l & 15, lc = ((l >> 4) << 3) + j;
        float val;
        if (idx < 49152) {
            const float* W; int off;
            if (idx < 16384)      { W = Wsp; off = idx; }
            else if (idx < 32768) { W = Wge; off = idx - 16384; }
            else                  { W = Wtm; off = idx - 32768; }
            int t = off >> 9, kk = t & 7, nb = t >> 3;
            val = W[(nb * 16 + lr) * 256 + kk * 32 + lc];
        } else if (idx < 53248) {
            int t = (idx - 49152) >> 9, kk = t & 1, nb = t >> 1;
            val = gatW[(nb * 16 + lr) * 64 + kk * 32 + lc];
        } else if (idx < 61440) {
            int t = (idx - 53248) >> 9, kk = t & 1, nb = t >> 1;
            val = inw[(nb * 16 + lr) * 64 + kk * 32 + lc];
        } else if (idx < 69632) {
            int t = (idx - 61440) >> 9, kk = t & 1, nbh = t >> 1;
            int h = nbh >> 2, nb = nbh & 3;
            int r = nb * 16 + lr, c = kk * 32 + lc;
            float s = 0.f;
            for (int k = 0; k < 32; ++k)
                s += outw[r * 64 + h * 32 + k] * inw[(128 + h * 32 + k) * 64 + c];
            val = s;
        } else if (idx < 71680) {
            int t = (idx - 69632) >> 9, kk = t & 1, nb = t >> 1;
            val = p1w[(nb * 16 + lr) * 64 + kk * 32 + lc];
        } else {
            val = p2w[lr * 32 + lc];
        }
        ws[idx] = f2bf(val);
    } else if (idx < 72256) {
        int r = idx - 72192;
        float s = out_b[r];
        for (int k = 0; k < 64; ++k) s += outw[r * 64 + 128 + k] * in_b[128 + k];
        ((float*)(ws + 72192))[r] = s;
    }
}

// ---------------------------------------------------------------------------
// Fused main kernel. 256 threads = 4 waves; each wave owns 16 samples
// end-to-end. All LDS wave-private -> no __syncthreads.
// ---------------------------------------------------------------------------
__global__ __launch_bounds__(256)
void giman_main(const float* __restrict__ spatial, const float* __restrict__ genomic,
                const float* __restrict__ temporal, const float* __restrict__ adj,
                const short* __restrict__ wf,
                const float* __restrict__ bsp, const float* __restrict__ bge,
                const float* __restrict__ btm, const float* __restrict__ gat_a,
                const float* __restrict__ in_b, const float* __restrict__ ln_g,
                const float* __restrict__ ln_b, const float* __restrict__ p1b,
                const float* __restrict__ p2b, const float* __restrict__ p3w,
                const float* __restrict__ p3bb,
                float* __restrict__ dout, int Btot)
{
    __shared__ __align__(16) short x_lds[4][48][72];  // x (16 samp x 3 nodes); z1 overlaid later
    __shared__ __align__(16) short c_lds[4][16][72];  // combined (16 samp x 64)
    __shared__ __align__(16) float a_lds[4][148];     // adj (16 samp x 9)

    const int wv   = threadIdx.x >> 6;
    const int lane = threadIdx.x & 63;
    const int lq   = lane & 15;
    const int lg   = lane >> 4;
    const int s0   = blockIdx.x * 64 + wv * 16;
    if (s0 + 16 > Btot) return;

    short (*xw)[72] = x_lds[wv];

    // prefetch adj for all 16 samples (hidden under phase 1)
    if (lane < 36)
        *(float4*)&a_lds[wv][lane * 4] = *(const float4*)(adj + (size_t)s0 * 9 + lane * 4);

    // ---- per-lane constants (col = nb*16+lq) ----
    const float* cbp = (const float*)(wf + 72192);
    float a1v[4], a2v[4], cbv[4], lgv[4], lbv[4], ibv[8];
#pragma unroll
    for (int nb = 0; nb < 4; ++nb) {
        int c = nb * 16 + lq;
        a1v[nb] = gat_a[c & 31];
        a2v[nb] = gat_a[32 + (c & 31)];
        cbv[nb] = cbp[c];
        lgv[nb] = ln_g[c];
        lbv[nb] = ln_b[c];
    }
#pragma unroll
    for (int nb = 0; nb < 8; ++nb) ibv[nb] = in_b[nb * 16 + lq];
    const float inv3 = 1.f / 3.f;

    // ================= Phase 1: modality projections (K=256) =================
    {
        const float* Xs[3] = {spatial, genomic, temporal};
        const float* Bs[3] = {bsp, bge, btm};
#pragma unroll
        for (int m = 0; m < 3; ++m) {
            const float* X = Xs[m] + (size_t)(s0 + lq) * 256 + lg * 8;
            const v8s* bwf = (const v8s*)(wf + m * 16384);
            v4f acc[4];
#pragma unroll
            for (int nb = 0; nb < 4; ++nb) acc[nb] = (v4f){0.f, 0.f, 0.f, 0.f};
#pragma unroll 4
            for (int kk = 0; kk < 8; ++kk) {
                float4 u = *(const float4*)(X + kk * 32);
                float4 v = *(const float4*)(X + kk * 32 + 4);
                v8s af;
                af[0] = f2bf(u.x); af[1] = f2bf(u.y); af[2] = f2bf(u.z); af[3] = f2bf(u.w);
                af[4] = f2bf(v.x); af[5] = f2bf(v.y); af[6] = f2bf(v.z); af[7] = f2bf(v.w);
#pragma unroll
                for (int nb = 0; nb < 4; ++nb)
                    acc[nb] = MFMA16(af, bwf[(nb * 8 + kk) * 64 + lane], acc[nb]);
            }
#pragma unroll
            for (int nb = 0; nb < 4; ++nb) {
                float bb = Bs[m][nb * 16 + lq];
#pragma unroll
                for (int r = 0; r < 4; ++r) {
                    float v = acc[nb][r] + bb;
                    v = v > 0.f ? v : 0.f;                       // ReLU
                    xw[(lg * 4 + r) * 3 + m][nb * 16 + lq] = f2bf(v);
                }
            }
        }
    }

    // ================= Phase 2: per 4-sample tile =================
    const v8s* gwf = (const v8s*)(wf + 49152);
    const v8s* qkf = (const v8s*)(wf + 53248);
    const v8s* uf  = (const v8s*)(wf + 61440);

#pragma unroll 1
    for (int t = 0; t < 4; ++t) {
        // A-fragments of x (rows: 4 per sample, node clamped)
        int rn = lq & 3; rn = (rn == 3) ? 2 : rn;
        const short* xrp = xw[(t * 4 + (lq >> 2)) * 3 + rn];
        v8s xa0 = *(const v8s*)(xrp + lg * 8);
        v8s xa1 = *(const v8s*)(xrp + 32 + lg * 8);

        // ---- GAT: h = x @ gatW^T; attention; gp[4] ----
        float gp[4];
        {
            v4f hacc[4];
#pragma unroll
            for (int nb = 0; nb < 4; ++nb) {
                v4f a = (v4f){0.f, 0.f, 0.f, 0.f};
                a = MFMA16(xa0, gwf[(nb * 2 + 0) * 64 + lane], a);
                a = MFMA16(xa1, gwf[(nb * 2 + 1) * 64 + lane], a);
                hacc[nb] = a;
            }
            float ei[3][2] = {}, ej[3][2] = {};
#pragma unroll
            for (int nb = 0; nb < 4; ++nb) {
                int h = nb >> 1;
#pragma unroll
                for (int n = 0; n < 3; ++n) {
                    ei[n][h] += hacc[nb][n] * a1v[nb];
                    ej[n][h] += hacc[nb][n] * a2v[nb];
                }
            }
#pragma unroll
            for (int n = 0; n < 3; ++n)
#pragma unroll
                for (int h = 0; h < 2; ++h) { ei[n][h] = bfly16(ei[n][h]); ej[n][h] = bfly16(ej[n][h]); }

            const float* amp = &a_lds[wv][(t * 4 + lg) * 9];
            float wj0[2] = {}, wj1[2] = {}, wj2[2] = {};
#pragma unroll
            for (int h = 0; h < 2; ++h)
#pragma unroll
                for (int i = 0; i < 3; ++i) {
                    float e0 = ei[i][h] + ej[0][h]; e0 = e0 > 0.f ? e0 : 0.2f * e0; if (amp[i * 3 + 0] == 0.f) e0 = -1e9f;
                    float e1 = ei[i][h] + ej[1][h]; e1 = e1 > 0.f ? e1 : 0.2f * e1; if (amp[i * 3 + 1] == 0.f) e1 = -1e9f;
                    float e2 = ei[i][h] + ej[2][h]; e2 = e2 > 0.f ? e2 : 0.2f * e2; if (amp[i * 3 + 2] == 0.f) e2 = -1e9f;
                    float mx = fmaxf(e0, fmaxf(e1, e2));
                    float q0 = __expf(e0 - mx), q1 = __expf(e1 - mx), q2 = __expf(e2 - mx);
                    float inv = 1.f / (q0 + q1 + q2);
                    wj0[h] += q0 * inv; wj1[h] += q1 * inv; wj2[h] += q2 * inv;
                }
#pragma unroll
            for (int nb = 0; nb < 4; ++nb) {
                int h = nb >> 1;
                gp[nb] = (wj0[h] * hacc[nb][0] + wj1[h] * hacc[nb][1] + wj2[h] * hacc[nb][2]) * inv3;
            }
        }

        // ---- MHA scores + softmax, one head at a time (low live-reg) ----
        float al[2][9];
#pragma unroll
        for (int h = 0; h < 2; ++h) {
            v4f q0, q1, k0, k1;
            {
                float b0 = ibv[2 * h], b1 = ibv[2 * h + 1];
                float b2 = ibv[4 + 2 * h], b3 = ibv[5 + 2 * h];
                q0 = (v4f){b0, b0, b0, b0};
                q1 = (v4f){b1, b1, b1, b1};
                k0 = (v4f){b2, b2, b2, b2};
                k1 = (v4f){b3, b3, b3, b3};
            }
            q0 = MFMA16(xa0, qkf[((2 * h) * 2 + 0) * 64 + lane], q0);
            q0 = MFMA16(xa1, qkf[((2 * h) * 2 + 1) * 64 + lane], q0);
            q1 = MFMA16(xa0, qkf[((2 * h + 1) * 2 + 0) * 64 + lane], q1);
            q1 = MFMA16(xa1, qkf[((2 * h + 1) * 2 + 1) * 64 + lane], q1);
            k0 = MFMA16(xa0, qkf[((4 + 2 * h) * 2 + 0) * 64 + lane], k0);
            k0 = MFMA16(xa1, qkf[((4 + 2 * h) * 2 + 1) * 64 + lane], k0);
            k1 = MFMA16(xa0, qkf[((5 + 2 * h) * 2 + 0) * 64 + lane], k1);
            k1 = MFMA16(xa1, qkf[((5 + 2 * h) * 2 + 1) * 64 + lane], k1);

            float s_[9];
#pragma unroll
            for (int i = 0; i < 3; ++i)
#pragma unroll
                for (int j = 0; j < 3; ++j)
                    s_[i * 3 + j] = bfly16(q0[i] * k0[j] + q1[i] * k1[j]);
#pragma unroll
            for (int i = 0; i < 3; ++i) {
                float e0 = s_[i * 3 + 0] * 0.17677669529663687f;
                float e1 = s_[i * 3 + 1] * 0.17677669529663687f;
                float e2 = s_[i * 3 + 2] * 0.17677669529663687f;
                float mx = fmaxf(e0, fmaxf(e1, e2));
                float w0 = __expf(e0 - mx), w1 = __expf(e1 - mx), w2 = __expf(e2 - mx);
                float inv = 1.f / (w0 + w1 + w2);
                al[h][i * 3 + 0] = w0 * inv;
                al[h][i * 3 + 1] = w1 * inv;
                al[h][i * 3 + 2] = w2 * inv;
            }
        }

        // ---- y = x + cb + sum_h attn_h; u computed per (h,nb) and folded ----
        float y[4][3];
#pragma unroll
        for (int nb = 0; nb < 4; ++nb)
#pragma unroll
            for (int r = 0; r < 3; ++r)
                y[nb][r] = bf2f(xw[(t * 4 + lg) * 3 + r][nb * 16 + lq]) + cbv[nb];
#pragma unroll
        for (int h = 0; h < 2; ++h)
#pragma unroll
            for (int nb = 0; nb < 4; ++nb) {
                v4f u = (v4f){0.f, 0.f, 0.f, 0.f};
                u = MFMA16(xa0, uf[((h * 4 + nb) * 2 + 0) * 64 + lane], u);
                u = MFMA16(xa1, uf[((h * 4 + nb) * 2 + 1) * 64 + lane], u);
#pragma unroll
                for (int r = 0; r < 3; ++r)
                    y[nb][r] += al[h][r * 3 + 0] * u[0] + al[h][r * 3 + 1] * u[1]
                              + al[h][r * 3 + 2] * u[2];
            }

        // ---- LayerNorm per node row + cross-modal mean + combine with GAT ----
        float mu[3], rs[3];
#pragma unroll
        for (int r = 0; r < 3; ++r) {
            float sm = y[0][r] + y[1][r] + y[2][r] + y[3][r];
            float sq = y[0][r] * y[0][r] + y[1][r] * y[1][r]
                     + y[2][r] * y[2][r] + y[3][r] * y[3][r];
            sm = bfly16(sm); sq = bfly16(sq);
            float m_ = sm * (1.f / 64.f);
            float var = sq * (1.f / 64.f) - m_ * m_;
            mu[r] = m_;
            rs[r] = rsqrtf(var + 1e-5f);
        }
#pragma unroll
        for (int nb = 0; nb < 4; ++nb) {
            float cm = (y[nb][0] - mu[0]) * rs[0] + (y[nb][1] - mu[1]) * rs[1]
                     + (y[nb][2] - mu[2]) * rs[2];
            float comb = gp[nb] + cm * inv3 * lgv[nb] + lbv[nb];
            c_lds[wv][t * 4 + lg][nb * 16 + lq] = f2bf(comb);
        }
    }

    // ================= Predictor 64->32->16->2 via MFMA =================
    {
        const v8s* p1f = (const v8s*)(wf + 69632);
        const v8s* p2f = (const v8s*)(wf + 71680);
        short (*zw)[40] = (short (*)[40])(&x_lds[wv][0][0]);   // x region is dead now
        const short* crp = &c_lds[wv][lq][0];
        v8s ca0 = *(const v8s*)(crp + lg * 8);
        v8s ca1 = *(const v8s*)(crp + 32 + lg * 8);
        const float pb1v0 = p1b[lq], pb1v1 = p1b[16 + lq], pb2v = p2b[lq];
        const float p3w0 = p3w[lq], p3w1 = p3w[16 + lq];
        v4f z1[2];
#pragma unroll
        for (int nb = 0; nb < 2; ++nb) {
            float bb = nb ? pb1v1 : pb1v0;
            v4f a = (v4f){bb, bb, bb, bb};
            a = MFMA16(ca0, p1f[(nb * 2 + 0) * 64 + lane], a);
            a = MFMA16(ca1, p1f[(nb * 2 + 1) * 64 + lane], a);
            z1[nb] = a;
        }
#pragma unroll
        for (int nb = 0; nb < 2; ++nb)
#pragma unroll
            for (int r = 0; r < 4; ++r) {
                float v = z1[nb][r];
                v = v > 0.f ? v : 0.f;
                zw[lg * 4 + r][nb * 16 + lq] = f2bf(v);
            }
        v8s za = *(const v8s*)(&zw[lq][0] + lg * 8);
        v4f z2 = (v4f){pb2v, pb2v, pb2v, pb2v};
        z2 = MFMA16(za, p2f[lane], z2);
        const float p3b0 = p3bb[0], p3b1 = p3bb[1];
#pragma unroll
        for (int r = 0; r < 4; ++r) {
            float v = z2[r];
            v = v > 0.f ? v : 0.f;
            float po0 = bfly16(v * p3w0);
            float po1 = bfly16(v * p3w1);
            if (lq == 0) {
                dout[s0 + lg * 4 + r] = po0 + p3b0;
                dout[Btot + s0 + lg * 4 + r] = po1 + p3b1;
            }
        }
    }
}

extern "C" void kernel_launch(void* const* d_in, const int* in_sizes, int n_in,
                              void* d_out, int out_size, void* d_ws, size_t ws_size,
                              hipStream_t stream) {
    const float* spatial  = (const float*)d_in[0];
    const float* genomic  = (const float*)d_in[1];
    const float* temporal = (const float*)d_in[2];
    const float* adj      = (const float*)d_in[3];
    const float* Wsp = (const float*)d_in[4];
    const float* bsp = (const float*)d_in[5];
    const float* Wge = (const float*)d_in[6];
    const float* bge = (const float*)d_in[7];
    const float* Wtm = (const float*)d_in[8];
    const float* btm = (const float*)d_in[9];
    const float* gatW  = (const float*)d_in[10];
    const float* gat_a = (const float*)d_in[11];
    const float* in_w  = (const float*)d_in[12];
    const float* in_b  = (const float*)d_in[13];
    const float* out_w = (const float*)d_in[14];
    const float* out_b = (const float*)d_in[15];
    const float* ln_g  = (const float*)d_in[16];
    const float* ln_b  = (const float*)d_in[17];
    const float* p1w = (const float*)d_in[18];
    const float* p1b = (const float*)d_in[19];
    const float* p2w = (const float*)d_in[20];
    const float* p2b = (const float*)d_in[21];
    const float* p3w = (const float*)d_in[22];
    const float* p3b = (const float*)d_in[23];
    float* out = (float*)d_out;
    const int Btot = in_sizes[0] / 256;

    short* wf = (short*)d_ws;

    giman_prep<<<(72256 + 255) / 256, 256, 0, stream>>>(Wsp, Wge, Wtm, gatW, in_w, out_w,
                                                        p1w, p2w, in_b, out_b, wf);
    giman_main<<<Btot / 64, 256, 0, stream>>>(spatial, genomic, temporal, adj, wf,
                                              bsp, bge, btm, gat_a, in_b,
                                              ln_g, ln_b, p1b, p2b, p3w, p3b,
                                              out, Btot);
}

// Round 4
// 207.720 us; speedup vs baseline: 2.9951x; 1.1324x over previous
//
#include <hip/hip_runtime.h>

typedef __attribute__((ext_vector_type(8))) short v8s;   // 8 x bf16 bits
typedef __attribute__((ext_vector_type(4))) float v4f;   // MFMA accumulator

#define MFMA16(a, b, c) __builtin_amdgcn_mfma_f32_16x16x32_bf16((a), (b), (c), 0, 0, 0)
#define SCQ 0.17677669529663687f

__device__ __forceinline__ short f2bf(float f) {
    unsigned u = __float_as_uint(f);
    u += 0x7FFFu + ((u >> 16) & 1u);          // round-to-nearest-even
    return (short)(u >> 16);
}
__device__ __forceinline__ float bf2f(short s) {
    return __uint_as_float(((unsigned)(unsigned short)s) << 16);
}
__device__ __forceinline__ float bfly16(float v) {
#pragma unroll
    for (int m = 1; m < 16; m <<= 1) v += __shfl_xor(v, m);
    return v;
}

// ---------------------------------------------------------------------------
// Weight prep. ws layout (shorts):
//   [0)      wsp frags 16384      (nb0..3, kk0..7)
//   [16384)  wge frags 16384
//   [32768)  wtm frags 16384
//   [49152)  gatW+e frags 5120    (nb0..4, kk0..1; nb4 cols: g1h0,g1h1,g2h0,g2h1)
//   [54272)  q,k frags 8192       (in_w rows 0..127; q rows pre-scaled by 1/sqrt(32))
//   [62464)  u frags 8192         (M_h = outW_h @ Wv_h: h0..1, nb0..3, kk0..1)
//   [70656)  p1 frags 2048
//   [72704)  p2 frags 512
//   [73216)  cb[64] f32           (out_b + out_w[:,v-part] @ in_b[v-part])
// frag element: ws[base + (t*64 + l)*8 + j] = bf16(W[nb*16+(l&15)][kk*32+(l>>4)*8+j])
// ---------------------------------------------------------------------------
__global__ void giman_prep(const float* __restrict__ Wsp, const float* __restrict__ Wge,
                           const float* __restrict__ Wtm, const float* __restrict__ gatW,
                           const float* __restrict__ gat_a,
                           const float* __restrict__ inw, const float* __restrict__ outw,
                           const float* __restrict__ p1w, const float* __restrict__ p2w,
                           const float* __restrict__ in_b, const float* __restrict__ out_b,
                           short* __restrict__ ws) {
    int idx = blockIdx.x * 256 + threadIdx.x;
    if (idx < 73216) {
        int j = idx & 7, l = (idx >> 3) & 63;
        int lr = l & 15, lc = ((l >> 4) << 3) + j;
        float val;
        if (idx < 49152) {
            const float* W; int off;
            if (idx < 16384)      { W = Wsp; off = idx; }
            else if (idx < 32768) { W = Wge; off = idx - 16384; }
            else                  { W = Wtm; off = idx - 32768; }
            int t = off >> 9, kk = t & 7, nb = t >> 3;
            val = W[(nb * 16 + lr) * 256 + kk * 32 + lc];
        } else if (idx < 54272) {
            int t = (idx - 49152) >> 9, kk = t & 1, nb = t >> 1;
            if (nb < 4) {
                val = gatW[(nb * 16 + lr) * 64 + kk * 32 + lc];
            } else {
                val = 0.f;
                if (lr < 4) {
                    int f = kk * 32 + lc;
                    float s = 0.f;
                    for (int d = 0; d < 32; ++d)
                        s += gat_a[(lr >> 1) * 32 + d] * gatW[((lr & 1) * 32 + d) * 64 + f];
                    val = s;
                }
            }
        } else if (idx < 62464) {
            int t = (idx - 54272) >> 9, kk = t & 1, nb = t >> 1;
            int row = nb * 16 + lr;
            val = inw[row * 64 + kk * 32 + lc] * (row < 64 ? SCQ : 1.f);
        } else if (idx < 70656) {
            int t = (idx - 62464) >> 9, kk = t & 1, nbh = t >> 1;
            int h = nbh >> 2, nb = nbh & 3;
            int r = nb * 16 + lr, c = kk * 32 + lc;
            float s = 0.f;
            for (int k = 0; k < 32; ++k)
                s += outw[r * 64 + h * 32 + k] * inw[(128 + h * 32 + k) * 64 + c];
            val = s;
        } else if (idx < 72704) {
            int t = (idx - 70656) >> 9, kk = t & 1, nb = t >> 1;
            val = p1w[(nb * 16 + lr) * 64 + kk * 32 + lc];
        } else {
            val = p2w[lr * 32 + lc];
        }
        ws[idx] = f2bf(val);
    } else if (idx < 73280) {
        int r = idx - 73216;
        float s = out_b[r];
        for (int k = 0; k < 64; ++k) s += outw[r * 64 + 128 + k] * in_b[128 + k];
        ((float*)(ws + 73216))[r] = s;
    }
}

// ---------------------------------------------------------------------------
// Fused main kernel. 256 threads = 4 waves; each wave owns 16 samples
// end-to-end. All LDS wave-private -> no __syncthreads.
// ---------------------------------------------------------------------------
__global__ __launch_bounds__(256)
void giman_main(const float* __restrict__ spatial, const float* __restrict__ genomic,
                const float* __restrict__ temporal, const float* __restrict__ adj,
                const short* __restrict__ wf,
                const float* __restrict__ bsp, const float* __restrict__ bge,
                const float* __restrict__ btm,
                const float* __restrict__ in_b, const float* __restrict__ ln_g,
                const float* __restrict__ ln_b, const float* __restrict__ p1b,
                const float* __restrict__ p2b, const float* __restrict__ p3w,
                const float* __restrict__ p3bb,
                float* __restrict__ dout, int Btot)
{
    __shared__ __align__(16) short x_lds[4][48][72];  // x (16 samp x 3 nodes); z1 overlaid later
    __shared__ __align__(16) short c_lds[4][16][72];  // combined (16 samp x 64)
    __shared__ __align__(16) short q_tr[4][16][72];   // q transpose buf [q-idx][feat64]
    __shared__ __align__(16) short k_tr[4][16][72];   // k transpose buf
    __shared__ __align__(16) float a_lds[4][148];     // adj (16 samp x 9)

    const int wv   = threadIdx.x >> 6;
    const int lane = threadIdx.x & 63;
    const int lq   = lane & 15;
    const int lg   = lane >> 4;
    const int grpb = lane & 48;       // 16*lg
    const int s0   = blockIdx.x * 64 + wv * 16;
    if (s0 + 16 > Btot) return;

    short (*xw)[72] = x_lds[wv];
    short (*qtr)[72] = q_tr[wv];
    short (*ktr)[72] = k_tr[wv];

    // prefetch adj for all 16 samples (hidden under phase 1)
    if (lane < 36)
        *(float4*)&a_lds[wv][lane * 4] = *(const float4*)(adj + (size_t)s0 * 9 + lane * 4);

    // zero the pad rows of q/k transpose bufs (never written per-tile)
#pragma unroll
    for (int nb = 0; nb < 4; ++nb) {
        qtr[lg * 4 + 3][nb * 16 + lq] = 0;
        ktr[lg * 4 + 3][nb * 16 + lq] = 0;
    }

    // ---- per-lane constants (col = nb*16+lq) ----
    const float* cbp = (const float*)(wf + 73216);
    float cbv[4], lgv[4], lbv[4], ibv[8];
#pragma unroll
    for (int nb = 0; nb < 4; ++nb) {
        int c = nb * 16 + lq;
        cbv[nb] = cbp[c];
        lgv[nb] = ln_g[c];
        lbv[nb] = ln_b[c];
    }
#pragma unroll
    for (int nb = 0; nb < 8; ++nb)
        ibv[nb] = in_b[nb * 16 + lq] * (nb < 4 ? SCQ : 1.f);
    const float inv3 = 1.f / 3.f;

    // ================= Phase 1: modality projections (K=256) =================
    {
        const float* Xs[3] = {spatial, genomic, temporal};
        const float* Bs[3] = {bsp, bge, btm};
#pragma unroll
        for (int m = 0; m < 3; ++m) {
            const float* X = Xs[m] + (size_t)(s0 + lq) * 256 + lg * 8;
            const v8s* bwf = (const v8s*)(wf + m * 16384);
            v4f acc[4];
#pragma unroll
            for (int nb = 0; nb < 4; ++nb) acc[nb] = (v4f){0.f, 0.f, 0.f, 0.f};
#pragma unroll 4
            for (int kk = 0; kk < 8; ++kk) {
                float4 u = *(const float4*)(X + kk * 32);
                float4 v = *(const float4*)(X + kk * 32 + 4);
                v8s af;
                af[0] = f2bf(u.x); af[1] = f2bf(u.y); af[2] = f2bf(u.z); af[3] = f2bf(u.w);
                af[4] = f2bf(v.x); af[5] = f2bf(v.y); af[6] = f2bf(v.z); af[7] = f2bf(v.w);
#pragma unroll
                for (int nb = 0; nb < 4; ++nb)
                    acc[nb] = MFMA16(af, bwf[(nb * 8 + kk) * 64 + lane], acc[nb]);
            }
#pragma unroll
            for (int nb = 0; nb < 4; ++nb) {
                float bb = Bs[m][nb * 16 + lq];
#pragma unroll
                for (int r = 0; r < 4; ++r) {
                    float v = acc[nb][r] + bb;
                    v = v > 0.f ? v : 0.f;                       // ReLU
                    xw[(lg * 4 + r) * 3 + m][nb * 16 + lq] = f2bf(v);
                }
            }
        }
    }

    // ================= Phase 2: per 4-sample tile =================
    const v8s* gwf = (const v8s*)(wf + 49152);
    const v8s* qkf = (const v8s*)(wf + 54272);
    const v8s* uf  = (const v8s*)(wf + 62464);

#pragma unroll 1
    for (int t = 0; t < 4; ++t) {
        // A-fragments of x (rows: 4 per sample, node clamped)
        int rn = lq & 3; rn = (rn == 3) ? 2 : rn;
        const short* xrp = xw[(t * 4 + (lq >> 2)) * 3 + rn];
        v8s xa0 = *(const v8s*)(xrp + lg * 8);
        v8s xa1 = *(const v8s*)(xrp + 32 + lg * 8);

        // ---- GAT: h + e-values via MFMA (nb=4 block); broadcasts; gp[4] ----
        float gp[4];
        {
            v4f hacc[4];
#pragma unroll
            for (int nb = 0; nb < 4; ++nb) {
                v4f a = (v4f){0.f, 0.f, 0.f, 0.f};
                a = MFMA16(xa0, gwf[(nb * 2 + 0) * 64 + lane], a);
                a = MFMA16(xa1, gwf[(nb * 2 + 1) * 64 + lane], a);
                hacc[nb] = a;
            }
            v4f eacc = (v4f){0.f, 0.f, 0.f, 0.f};
            eacc = MFMA16(xa0, gwf[8 * 64 + lane], eacc);
            eacc = MFMA16(xa1, gwf[9 * 64 + lane], eacc);

            // e for this lane's sample lg: ei[r][h] at col h, ej[r][h] at col 2+h
            float eiv[3][2], ejv[3][2];
#pragma unroll
            for (int r = 0; r < 3; ++r) {
#pragma unroll
                for (int h = 0; h < 2; ++h) {
                    eiv[r][h] = __shfl(eacc[r], grpb + h);
                    ejv[r][h] = __shfl(eacc[r], grpb + 2 + h);
                }
            }

            const float* amp = &a_lds[wv][(t * 4 + lg) * 9];
            float wj0[2] = {}, wj1[2] = {}, wj2[2] = {};
#pragma unroll
            for (int h = 0; h < 2; ++h)
#pragma unroll
                for (int i = 0; i < 3; ++i) {
                    float e0 = eiv[i][h] + ejv[0][h]; e0 = e0 > 0.f ? e0 : 0.2f * e0; if (amp[i * 3 + 0] == 0.f) e0 = -1e9f;
                    float e1 = eiv[i][h] + ejv[1][h]; e1 = e1 > 0.f ? e1 : 0.2f * e1; if (amp[i * 3 + 1] == 0.f) e1 = -1e9f;
                    float e2 = eiv[i][h] + ejv[2][h]; e2 = e2 > 0.f ? e2 : 0.2f * e2; if (amp[i * 3 + 2] == 0.f) e2 = -1e9f;
                    float mx = fmaxf(e0, fmaxf(e1, e2));
                    float q0 = __expf(e0 - mx), q1 = __expf(e1 - mx), q2 = __expf(e2 - mx);
                    float inv = 1.f / (q0 + q1 + q2);
                    wj0[h] += q0 * inv; wj1[h] += q1 * inv; wj2[h] += q2 * inv;
                }
#pragma unroll
            for (int nb = 0; nb < 4; ++nb) {
                int h = nb >> 1;
                gp[nb] = (wj0[h] * hacc[nb][0] + wj1[h] * hacc[nb][1] + wj2[h] * hacc[nb][2]) * inv3;
            }
        }

        // ---- q,k via MFMA; transpose through LDS (bf16) ----
        {
            v4f qa[4], ka[4];
#pragma unroll
            for (int nb = 0; nb < 4; ++nb) {
                float bb = ibv[nb];
                v4f a = (v4f){bb, bb, bb, bb};
                a = MFMA16(xa0, qkf[(nb * 2 + 0) * 64 + lane], a);
                a = MFMA16(xa1, qkf[(nb * 2 + 1) * 64 + lane], a);
                qa[nb] = a;
            }
#pragma unroll
            for (int nb = 0; nb < 4; ++nb) {
                float bb = ibv[4 + nb];
                v4f a = (v4f){bb, bb, bb, bb};
                a = MFMA16(xa0, qkf[((4 + nb) * 2 + 0) * 64 + lane], a);
                a = MFMA16(xa1, qkf[((4 + nb) * 2 + 1) * 64 + lane], a);
                ka[nb] = a;
            }
#pragma unroll
            for (int nb = 0; nb < 4; ++nb)
#pragma unroll
                for (int r = 0; r < 3; ++r) {
                    qtr[lg * 4 + r][nb * 16 + lq] = f2bf(qa[nb][r]);
                    ktr[lg * 4 + r][nb * 16 + lq] = f2bf(ka[nb][r]);
                }
        }

        // ---- score MFMA per head + broadcast + softmax ----
        float al[2][9];
        {
            const int sb = grpb + (grpb >> 2);   // 20*lg
#pragma unroll
            for (int h = 0; h < 2; ++h) {
                v8s aq = *(const v8s*)&qtr[lq][h * 32 + lg * 8];
                v8s bk = *(const v8s*)&ktr[lq][h * 32 + lg * 8];
                v4f S = (v4f){0.f, 0.f, 0.f, 0.f};
                S = MFMA16(aq, bk, S);
                float sc[9];
#pragma unroll
                for (int i = 0; i < 3; ++i)
#pragma unroll
                    for (int j = 0; j < 3; ++j)
                        sc[i * 3 + j] = __shfl(S[i], sb + j);
#pragma unroll
                for (int i = 0; i < 3; ++i) {
                    float e0 = sc[i * 3 + 0], e1 = sc[i * 3 + 1], e2 = sc[i * 3 + 2];
                    float mx = fmaxf(e0, fmaxf(e1, e2));
                    float w0 = __expf(e0 - mx), w1 = __expf(e1 - mx), w2 = __expf(e2 - mx);
                    float inv = 1.f / (w0 + w1 + w2);
                    al[h][i * 3 + 0] = w0 * inv;
                    al[h][i * 3 + 1] = w1 * inv;
                    al[h][i * 3 + 2] = w2 * inv;
                }
            }
        }

        // ---- y = x + cb + sum_h attn_h; u computed per (h,nb) and folded ----
        float y[4][3];
#pragma unroll
        for (int nb = 0; nb < 4; ++nb)
#pragma unroll
            for (int r = 0; r < 3; ++r)
                y[nb][r] = bf2f(xw[(t * 4 + lg) * 3 + r][nb * 16 + lq]) + cbv[nb];
#pragma unroll
        for (int h = 0; h < 2; ++h)
#pragma unroll
            for (int nb = 0; nb < 4; ++nb) {
                v4f u = (v4f){0.f, 0.f, 0.f, 0.f};
                u = MFMA16(xa0, uf[((h * 4 + nb) * 2 + 0) * 64 + lane], u);
                u = MFMA16(xa1, uf[((h * 4 + nb) * 2 + 1) * 64 + lane], u);
#pragma unroll
                for (int r = 0; r < 3; ++r)
                    y[nb][r] += al[h][r * 3 + 0] * u[0] + al[h][r * 3 + 1] * u[1]
                              + al[h][r * 3 + 2] * u[2];
            }

        // ---- LayerNorm per node row + cross-modal mean + combine with GAT ----
        float mu[3], rs[3];
#pragma unroll
        for (int r = 0; r < 3; ++r) {
            float sm = y[0][r] + y[1][r] + y[2][r] + y[3][r];
            float sq = y[0][r] * y[0][r] + y[1][r] * y[1][r]
                     + y[2][r] * y[2][r] + y[3][r] * y[3][r];
            sm = bfly16(sm); sq = bfly16(sq);
            float m_ = sm * (1.f / 64.f);
            float var = sq * (1.f / 64.f) - m_ * m_;
            mu[r] = m_;
            rs[r] = rsqrtf(var + 1e-5f);
        }
#pragma unroll
        for (int nb = 0; nb < 4; ++nb) {
            float cm = (y[nb][0] - mu[0]) * rs[0] + (y[nb][1] - mu[1]) * rs[1]
                     + (y[nb][2] - mu[2]) * rs[2];
            float comb = gp[nb] + cm * inv3 * lgv[nb] + lbv[nb];
            c_lds[wv][t * 4 + lg][nb * 16 + lq] = f2bf(comb);
        }
    }

    // ================= Predictor 64->32->16->2 via MFMA =================
    {
        const v8s* p1f = (const v8s*)(wf + 70656);
        const v8s* p2f = (const v8s*)(wf + 72704);
        short (*zw)[40] = (short (*)[40])(&x_lds[wv][0][0]);   // x region is dead now
        const short* crp = &c_lds[wv][lq][0];
        v8s ca0 = *(const v8s*)(crp + lg * 8);
        v8s ca1 = *(const v8s*)(crp + 32 + lg * 8);
        const float pb1v0 = p1b[lq], pb1v1 = p1b[16 + lq], pb2v = p2b[lq];
        const float p3w0 = p3w[lq], p3w1 = p3w[16 + lq];
        v4f z1[2];
#pragma unroll
        for (int nb = 0; nb < 2; ++nb) {
            float bb = nb ? pb1v1 : pb1v0;
            v4f a = (v4f){bb, bb, bb, bb};
            a = MFMA16(ca0, p1f[(nb * 2 + 0) * 64 + lane], a);
            a = MFMA16(ca1, p1f[(nb * 2 + 1) * 64 + lane], a);
            z1[nb] = a;
        }
#pragma unroll
        for (int nb = 0; nb < 2; ++nb)
#pragma unroll
            for (int r = 0; r < 4; ++r) {
                float v = z1[nb][r];
                v = v > 0.f ? v : 0.f;
                zw[lg * 4 + r][nb * 16 + lq] = f2bf(v);
            }
        v8s za = *(const v8s*)(&zw[lq][0] + lg * 8);
        v4f z2 = (v4f){pb2v, pb2v, pb2v, pb2v};
        z2 = MFMA16(za, p2f[lane], z2);
        const float p3b0 = p3bb[0], p3b1 = p3bb[1];
#pragma unroll
        for (int r = 0; r < 4; ++r) {
            float v = z2[r];
            v = v > 0.f ? v : 0.f;
            float po0 = bfly16(v * p3w0);
            float po1 = bfly16(v * p3w1);
            if (lq == 0) {
                dout[s0 + lg * 4 + r] = po0 + p3b0;
                dout[Btot + s0 + lg * 4 + r] = po1 + p3b1;
            }
        }
    }
}

extern "C" void kernel_launch(void* const* d_in, const int* in_sizes, int n_in,
                              void* d_out, int out_size, void* d_ws, size_t ws_size,
                              hipStream_t stream) {
    const float* spatial  = (const float*)d_in[0];
    const float* genomic  = (const float*)d_in[1];
    const float* temporal = (const float*)d_in[2];
    const float* adj      = (const float*)d_in[3];
    const float* Wsp = (const float*)d_in[4];
    const float* bsp = (const float*)d_in[5];
    const float* Wge = (const float*)d_in[6];
    const float* bge = (const float*)d_in[7];
    const float* Wtm = (const float*)d_in[8];
    const float* btm = (const float*)d_in[9];
    const float* gatW  = (const float*)d_in[10];
    const float* gat_a = (const float*)d_in[11];
    const float* in_w  = (const float*)d_in[12];
    const float* in_b  = (const float*)d_in[13];
    const float* out_w = (const float*)d_in[14];
    const float* out_b = (const float*)d_in[15];
    const float* ln_g  = (const float*)d_in[16];
    const float* ln_b  = (const float*)d_in[17];
    const float* p1w = (const float*)d_in[18];
    const float* p1b = (const float*)d_in[19];
    const float* p2w = (const float*)d_in[20];
    const float* p2b = (const float*)d_in[21];
    const float* p3w = (const float*)d_in[22];
    const float* p3b = (const float*)d_in[23];
    float* out = (float*)d_out;
    const int Btot = in_sizes[0] / 256;

    short* wf = (short*)d_ws;

    giman_prep<<<(73280 + 255) / 256, 256, 0, stream>>>(Wsp, Wge, Wtm, gatW, gat_a,
                                                        in_w, out_w, p1w, p2w,
                                                        in_b, out_b, wf);
    giman_main<<<Btot / 64, 256, 0, stream>>>(spatial, genomic, temporal, adj, wf,
                                              bsp, bge, btm, in_b,
                                              ln_g, ln_b, p1b, p2b, p3w, p3b,
                                              out, Btot);
}